// Round 5
// baseline (269.081 us; speedup 1.0000x reference)
//
#include <hip/hip_runtime.h>
#include <hip/hip_bf16.h>
#include <stdint.h>

#define KN 32
#define D  128
#define NNODES 20000
#define GRID 2500
#define ITERS 4            // 2 nodes/iter * 4 iters * 2500 blocks = 20000
#define VOCAB 100000

typedef __bf16 bf16;
typedef __bf16 bf16x8 __attribute__((ext_vector_type(8)));
typedef float  f32x4  __attribute__((ext_vector_type(4)));

// bf16 e_u LDS layout: 8 chunks/node; chunk c (1024 B, one GL2LDS) holds rows
// {c, c+8, c+16, c+24} (256 B each) + 16 B pad -> 520 bf16 elems per chunk.
// Row r -> elem (r&7)*520 + (r>>3)*128.  A-frag b128 banks: ((r&7)*4 + col/4)%32
// -> 8 groups x 2 rows = 2-way = free.
#define CHUNK_E 520
#define EU_NODE_E (8 * CHUNK_E)      // 4160 bf16 per node
#define H_STRIDE 136                 // bf16 elems; 68 dw, %32=4

#define GL2LDS(src, dst) __builtin_amdgcn_global_load_lds(                 \
    (const __attribute__((address_space(1))) void*)(src),                  \
    (__attribute__((address_space(3))) void*)(dst), 16, 0, 0)

#define MFMA(a, b, c) __builtin_amdgcn_mfma_f32_16x16x32_bf16((a), (b), (c), 0, 0, 0)

// Raw workgroup barrier that only waits LDS ops (keeps GL2LDS gather in flight).
__device__ __forceinline__ void bar_lds() {
    asm volatile("s_waitcnt lgkmcnt(0)" ::: "memory");
    __builtin_amdgcn_s_barrier();
    asm volatile("" ::: "memory");
}

// ---------------------------------------------------------------------------
// Pack W1/W2 fp32 -> bf16 MFMA B-fragment order (lane holds B[k=quad*8+j][n=lane&15]).
// ---------------------------------------------------------------------------
__global__ __launch_bounds__(256) void pack_weights_kernel(
    const float* __restrict__ W1, const float* __restrict__ W2,
    bf16* __restrict__ w1p, bf16* __restrict__ w2p)
{
    int t = blockIdx.x * 256 + threadIdx.x;
    if (t < 32768) {
        int j = t & 7, lane = (t >> 3) & 63, kt = (t >> 9) & 7, nt = t >> 12;
        int d = nt * 16 + (lane & 15);
        int f = kt * 32 + ((lane >> 4) << 3) + j;
        w1p[t] = (bf16)W1[d * 256 + f];
    } else if (t < 49152) {
        int u = t - 32768;
        int j = u & 7, lane = (u >> 3) & 63, kt = (u >> 9) & 3, nt = u >> 11;
        int e  = nt * 16 + (lane & 15);
        int dd = kt * 32 + ((lane >> 4) << 3) + j;
        w2p[u] = (bf16)W2[e * 128 + dd];
    }
}

// u2e fp32 -> bf16 row-major table (12.8M elems, 8/thread, 6250 blocks exact).
__global__ __launch_bounds__(256) void convert_table_kernel(
    const float* __restrict__ u2e, bf16* __restrict__ tbl)
{
    size_t i = ((size_t)blockIdx.x * 256 + threadIdx.x) * 8;
    float4 a = *(const float4*)(u2e + i);
    float4 b = *(const float4*)(u2e + i + 4);
    bf16x8 v;
    v[0]=(bf16)a.x; v[1]=(bf16)a.y; v[2]=(bf16)a.z; v[3]=(bf16)a.w;
    v[4]=(bf16)b.x; v[5]=(bf16)b.y; v[6]=(bf16)b.z; v[7]=(bf16)b.w;
    *(bf16x8*)(tbl + i) = v;
}

// ---------------------------------------------------------------------------
// Fast path: 4 waves, 2 nodes/iter, double-buffered bf16 gather.
// ---------------------------------------------------------------------------

// Issue 2-node gather into (EU, SF) using current gidx/sidx registers.
#define ISSUE_GATHER(EU, SF)                                                    \
    {                                                                           \
        _Pragma("unroll")                                                       \
        for (int j = 0; j < 4; ++j)                                             \
            GL2LDS(u2e_bf + (size_t)gidx[j] * D + ((lane & 15) << 3),           \
                   (EU) + gnd * EU_NODE_E + (cbase + j) * CHUNK_E);             \
        if (wave == 0)                                                          \
            GL2LDS(u2e + (size_t)sidx * D + ((lane & 31) << 2), (SF));          \
    }

// Load index block for node pair NP into gidx/sidx registers.
#define LOAD_IDX(NP)                                                            \
    {                                                                           \
        int nb_ = blockIdx.x * 8 + (NP) * 2;                                    \
        _Pragma("unroll")                                                       \
        for (int j = 0; j < 4; ++j)                                             \
            gidx[j] = neigh_idx[(nb_ + gnd) * KN + cbase + j + ((lane >> 4) << 3)]; \
        if (wave == 0) sidx = nodes[nb_ + (lane >> 5)];                         \
    }

#define STEP(IT, CEU, CSF, NEU, NSF)                                            \
    {                                                                           \
        const int nA   = blockIdx.x * 8 + (IT) * 2;                             \
        const int lenA = neigh_len[nA];                                         \
        const int lenB = neigh_len[nA + 1];                                     \
        if ((IT) < ITERS - 1) ISSUE_GATHER(NEU, NSF);                           \
        { int np_ = ((IT) + 2 < ITERS) ? (IT) + 2 : ITERS - 1; LOAD_IDX(np_); } \
        /* ---- layer 1 ---- */                                                 \
        _Pragma("unroll 1")                                                     \
        for (int nd = 0; nd < 2; ++nd) {                                        \
            const bf16*  euN = (CEU) + nd * EU_NODE_E;                          \
            const float* sfN = (CSF) + nd * D;                                  \
            bf16* h1N = h1 + nd * KN * H_STRIDE;                                \
            f32x4 c00 = {0.f,0.f,0.f,0.f}, c01 = c00, c10 = c00, c11 = c00;     \
            const int rb = (ln15 & 7) * CHUNK_E + (ln15 >> 3) * 128;            \
            _Pragma("unroll")                                                   \
            for (int ft = 0; ft < 4; ++ft) {                                    \
                bf16x8 a0 = *(const bf16x8*)(euN + rb + ft * 32 + quad * 8);    \
                bf16x8 a1 = *(const bf16x8*)(euN + rb + 256 + ft * 32 + quad * 8); \
                c00 = MFMA(a0, w1r[0][ft], c00);                                \
                c01 = MFMA(a0, w1r[1][ft], c01);                                \
                c10 = MFMA(a1, w1r[0][ft], c10);                                \
                c11 = MFMA(a1, w1r[1][ft], c11);                                \
            }                                                                   \
            _Pragma("unroll")                                                   \
            for (int ft = 4; ft < 8; ++ft) {                                    \
                int off = (ft - 4) * 32 + quad * 8;                             \
                f32x4 u0 = *(const f32x4*)(sfN + off);                          \
                f32x4 u1 = *(const f32x4*)(sfN + off + 4);                      \
                bf16x8 a;                                                       \
                _Pragma("unroll")                                               \
                for (int e = 0; e < 4; ++e) { a[e] = (bf16)u0[e]; a[4+e] = (bf16)u1[e]; } \
                c00 = MFMA(a, w1r[0][ft], c00);                                 \
                c01 = MFMA(a, w1r[1][ft], c01);                                 \
                c10 = MFMA(a, w1r[0][ft], c10);                                 \
                c11 = MFMA(a, w1r[1][ft], c11);                                 \
            }                                                                   \
            _Pragma("unroll")                                                   \
            for (int r = 0; r < 4; ++r) {                                       \
                int row = quad * 4 + r;                                         \
                h1N[row * H_STRIDE + nt0 * 16 + ln15]              = (bf16)fmaxf(c00[r] + bias1_0, 0.f); \
                h1N[row * H_STRIDE + (nt0 + 1) * 16 + ln15]        = (bf16)fmaxf(c01[r] + bias1_1, 0.f); \
                h1N[(16 + row) * H_STRIDE + nt0 * 16 + ln15]       = (bf16)fmaxf(c10[r] + bias1_0, 0.f); \
                h1N[(16 + row) * H_STRIDE + (nt0 + 1) * 16 + ln15] = (bf16)fmaxf(c11[r] + bias1_1, 0.f); \
            }                                                                   \
        }                                                                       \
        bar_lds();                                                              \
        /* ---- layer 2 + fused logits ---- */                                  \
        _Pragma("unroll 1")                                                     \
        for (int nd = 0; nd < 2; ++nd) {                                        \
            const bf16* h1N = h1 + nd * KN * H_STRIDE;                          \
            f32x4 d00 = {0.f,0.f,0.f,0.f}, d01 = d00, d10 = d00, d11 = d00;     \
            _Pragma("unroll")                                                   \
            for (int kt = 0; kt < 4; ++kt) {                                    \
                bf16x8 a0 = *(const bf16x8*)(h1N + ln15 * H_STRIDE + kt * 32 + quad * 8); \
                bf16x8 a1 = *(const bf16x8*)(h1N + (16 + ln15) * H_STRIDE + kt * 32 + quad * 8); \
                d00 = MFMA(a0, w2r[0][kt], d00);                                \
                d01 = MFMA(a0, w2r[1][kt], d01);                                \
                d10 = MFMA(a1, w2r[0][kt], d10);                                \
                d11 = MFMA(a1, w2r[1][kt], d11);                                \
            }                                                                   \
            _Pragma("unroll")                                                   \
            for (int r = 0; r < 4; ++r) {                                       \
                float p0 = w3_0 * fmaxf(d00[r] + bias2_0, 0.f)                  \
                         + w3_1 * fmaxf(d01[r] + bias2_1, 0.f);                 \
                float p1 = w3_0 * fmaxf(d10[r] + bias2_0, 0.f)                  \
                         + w3_1 * fmaxf(d11[r] + bias2_1, 0.f);                 \
                _Pragma("unroll")                                               \
                for (int o = 1; o < 16; o <<= 1) {                              \
                    p0 += __shfl_xor(p0, o);                                    \
                    p1 += __shfl_xor(p1, o);                                    \
                }                                                               \
                if (ln15 == 0) {                                                \
                    lpart[nd][wave * KN + quad * 4 + r]      = p0;              \
                    lpart[nd][wave * KN + 16 + quad * 4 + r] = p1;              \
                }                                                               \
            }                                                                   \
        }                                                                       \
        bar_lds();                                                              \
        /* ---- per-wave softmax + aggregation (wave w owns node w>>1) ---- */  \
        {                                                                       \
            int nd  = wave >> 1;                                                \
            int d   = ((wave & 1) << 6) + lane;                                 \
            int k   = lane & 31;                                                \
            float lg = lpart[nd][k] + lpart[nd][32 + k] + lpart[nd][64 + k]     \
                     + lpart[nd][96 + k] + b3v;                                 \
            int len = nd ? lenB : lenA;                                         \
            bool act = k < len;                                                 \
            float l = act ? lg : -1e30f;                                        \
            float m = l;                                                        \
            _Pragma("unroll")                                                   \
            for (int o = 1; o < 32; o <<= 1) m = fmaxf(m, __shfl_xor(m, o));    \
            float e = act ? expf(l - m) : 0.f;                                  \
            float s = e;                                                        \
            _Pragma("unroll")                                                   \
            for (int o = 1; o < 32; o <<= 1) s += __shfl_xor(s, o);             \
            float att = (s > 0.f) ? (e / s) : 0.f;                              \
            const bf16* euN = (CEU) + nd * EU_NODE_E;                           \
            float acc = 0.f;                                                    \
            _Pragma("unroll")                                                   \
            for (int k2 = 0; k2 < KN; ++k2) {                                   \
                float a  = __shfl(att, k2);                                     \
                float ev = (float)euN[(k2 & 7) * CHUNK_E + (k2 >> 3) * 128 + d]; \
                acc += a * ev;                                                  \
            }                                                                   \
            float sf = (CSF)[nd * D + d];                                       \
            out[(size_t)(nA + nd) * D + d] = (len > 0) ? 0.5f * (acc + sf) : sf; \
        }                                                                       \
        __syncthreads(); /* drains next-iter gather (late = hidden) + reuse fence */ \
    }

__global__ __launch_bounds__(256, 3) void graphrec_agg_kernel(
    const int*   __restrict__ nodes,
    const int*   __restrict__ neigh_idx,
    const int*   __restrict__ neigh_len,
    const float* __restrict__ u2e,
    const bf16*  __restrict__ u2e_bf,
    const float* __restrict__ b1,
    const float* __restrict__ b2,
    const float* __restrict__ W3,
    const float* __restrict__ b3,
    const bf16*  __restrict__ w1p,
    const bf16*  __restrict__ w2p,
    float*       __restrict__ out)
{
    __shared__ alignas(16) bf16  eu0[2 * EU_NODE_E];   // 16640 B
    __shared__ alignas(16) bf16  eu1[2 * EU_NODE_E];   // 16640 B
    __shared__ alignas(16) float sf0[2 * D];           // 1024 B
    __shared__ alignas(16) float sf1[2 * D];           // 1024 B
    __shared__ alignas(16) bf16  h1[2 * KN * H_STRIDE];// 17408 B
    __shared__ float lpart[2][4 * KN];                 // 1024 B

    const int t     = threadIdx.x;
    const int lane  = t & 63;
    const int wave  = t >> 6;
    const int ln15  = lane & 15;
    const int quad  = lane >> 4;
    const int nt0   = wave * 2;
    const int gnd   = wave >> 1;        // gather: node this wave stages
    const int cbase = (wave & 1) * 4;   // gather: first of 4 chunks

    const float bias1_0 = b1[nt0 * 16 + ln15];
    const float bias1_1 = b1[(nt0 + 1) * 16 + ln15];
    const float bias2_0 = b2[nt0 * 16 + ln15];
    const float bias2_1 = b2[(nt0 + 1) * 16 + ln15];
    const float w3_0    = W3[nt0 * 16 + ln15];
    const float w3_1    = W3[(nt0 + 1) * 16 + ln15];
    const float b3v     = b3[0];

    // resident weight fragments: 96 regs
    bf16x8 w1r[2][8];
    #pragma unroll
    for (int nt = 0; nt < 2; ++nt)
        #pragma unroll
        for (int ft = 0; ft < 8; ++ft)
            w1r[nt][ft] = *(const bf16x8*)(w1p + ((nt0 + nt) * 8 + ft) * 512 + lane * 8);
    bf16x8 w2r[2][4];
    #pragma unroll
    for (int nt = 0; nt < 2; ++nt)
        #pragma unroll
        for (int kt = 0; kt < 4; ++kt)
            w2r[nt][kt] = *(const bf16x8*)(w2p + ((nt0 + nt) * 4 + kt) * 512 + lane * 8);

    int gidx[4];
    int sidx = 0;

    LOAD_IDX(0);
    ISSUE_GATHER(eu0, sf0);
    LOAD_IDX(1);
    __syncthreads();   // pair-0 gather resident

    #pragma unroll 1
    for (int hi = 0; hi < ITERS; hi += 2) {
        STEP(hi,     eu0, sf0, eu1, sf1);
        STEP(hi + 1, eu1, sf1, eu0, sf0);
    }
}

// ---------------------------------------------------------------------------
// Fallback (round-4 kernel, fp32 gather) for small ws_size.
// ---------------------------------------------------------------------------
#define FB_CHUNK_DW 260
#define FB_EU_NODE_DW (16 * FB_CHUNK_DW)

__global__ __launch_bounds__(256, 3) void graphrec_agg_fb(
    const int*   __restrict__ nodes,
    const int*   __restrict__ neigh_idx,
    const int*   __restrict__ neigh_len,
    const float* __restrict__ u2e,
    const float* __restrict__ b1,
    const float* __restrict__ b2,
    const float* __restrict__ W3,
    const float* __restrict__ b3,
    const bf16*  __restrict__ w1p,
    const bf16*  __restrict__ w2p,
    float*       __restrict__ out)
{
    __shared__ alignas(16) float eu[2 * FB_EU_NODE_DW];
    __shared__ alignas(16) bf16  h1[2 * KN * H_STRIDE];
    __shared__ alignas(16) float self_f[2 * D];
    __shared__ float lpart[2][4 * KN];
    __shared__ float att_s[2][KN];

    const int t    = threadIdx.x;
    const int lane = t & 63;
    const int wave = t >> 6;
    const int ln15 = lane & 15;
    const int quad = lane >> 4;
    const int nt0  = wave * 2;

    const float bias1_0 = b1[nt0 * 16 + ln15];
    const float bias1_1 = b1[(nt0 + 1) * 16 + ln15];
    const float bias2_0 = b2[nt0 * 16 + ln15];
    const float bias2_1 = b2[(nt0 + 1) * 16 + ln15];
    const float w3_0    = W3[nt0 * 16 + ln15];
    const float w3_1    = W3[(nt0 + 1) * 16 + ln15];
    const float b3v     = b3[0];

    bf16x8 w1r[2][8];
    #pragma unroll
    for (int nt = 0; nt < 2; ++nt)
        #pragma unroll
        for (int ft = 0; ft < 8; ++ft)
            w1r[nt][ft] = *(const bf16x8*)(w1p + ((nt0 + nt) * 8 + ft) * 512 + lane * 8);
    bf16x8 w2r[2][4];
    #pragma unroll
    for (int nt = 0; nt < 2; ++nt)
        #pragma unroll
        for (int kt = 0; kt < 4; ++kt)
            w2r[nt][kt] = *(const bf16x8*)(w2p + ((nt0 + nt) * 4 + kt) * 512 + lane * 8);

    #pragma unroll 1
    for (int it = 0; it < ITERS; ++it) {
        const int nA   = blockIdx.x * 8 + it * 2;
        const int lenA = neigh_len[nA];
        const int lenB = neigh_len[nA + 1];
        {
            const int half = lane >> 5;
            const int colb = (lane & 31) << 4;
            #pragma unroll
            for (int nd = 0; nd < 2; ++nd) {
                #pragma unroll
                for (int j = 0; j < 4; ++j) {
                    int chunk = wave * 4 + j;
                    int idx = neigh_idx[(nA + nd) * KN + chunk + (half << 4)];
                    const char* src = (const char*)(u2e + (size_t)idx * D) + colb;
                    GL2LDS(src, eu + nd * FB_EU_NODE_DW + chunk * FB_CHUNK_DW);
                }
            }
            if (wave == 0) {
                int sidx = nodes[nA + half];
                const char* src = (const char*)(u2e + (size_t)sidx * D) + colb;
                GL2LDS(src, self_f);
            }
        }
        __syncthreads();
        #pragma unroll 1
        for (int nd = 0; nd < 2; ++nd) {
            const float* euN = eu + nd * FB_EU_NODE_DW;
            const float* sfN = self_f + nd * D;
            bf16* h1N = h1 + nd * KN * H_STRIDE;
            f32x4 c00 = {0.f,0.f,0.f,0.f}, c01 = c00, c10 = c00, c11 = c00;
            const int r0 = ln15 * FB_CHUNK_DW;
            #pragma unroll
            for (int ft = 0; ft < 4; ++ft) {
                int off = ft * 32 + quad * 8;
                f32x4 u0 = *(const f32x4*)(euN + r0 + off);
                f32x4 u1 = *(const f32x4*)(euN + r0 + off + 4);
                f32x4 v0 = *(const f32x4*)(euN + r0 + 128 + off);
                f32x4 v1 = *(const f32x4*)(euN + r0 + 128 + off + 4);
                bf16x8 a0, a1;
                #pragma unroll
                for (int e = 0; e < 4; ++e) {
                    a0[e] = (bf16)u0[e]; a0[4 + e] = (bf16)u1[e];
                    a1[e] = (bf16)v0[e]; a1[4 + e] = (bf16)v1[e];
                }
                c00 = MFMA(a0, w1r[0][ft], c00);
                c01 = MFMA(a0, w1r[1][ft], c01);
                c10 = MFMA(a1, w1r[0][ft], c10);
                c11 = MFMA(a1, w1r[1][ft], c11);
            }
            #pragma unroll
            for (int ft = 4; ft < 8; ++ft) {
                int off = (ft - 4) * 32 + quad * 8;
                f32x4 u0 = *(const f32x4*)(sfN + off);
                f32x4 u1 = *(const f32x4*)(sfN + off + 4);
                bf16x8 a;
                #pragma unroll
                for (int e = 0; e < 4; ++e) { a[e] = (bf16)u0[e]; a[4 + e] = (bf16)u1[e]; }
                c00 = MFMA(a, w1r[0][ft], c00);
                c01 = MFMA(a, w1r[1][ft], c01);
                c10 = MFMA(a, w1r[0][ft], c10);
                c11 = MFMA(a, w1r[1][ft], c11);
            }
            #pragma unroll
            for (int r = 0; r < 4; ++r) {
                int row = quad * 4 + r;
                h1N[row * H_STRIDE + nt0 * 16 + ln15]              = (bf16)fmaxf(c00[r] + bias1_0, 0.f);
                h1N[row * H_STRIDE + (nt0 + 1) * 16 + ln15]        = (bf16)fmaxf(c01[r] + bias1_1, 0.f);
                h1N[(16 + row) * H_STRIDE + nt0 * 16 + ln15]       = (bf16)fmaxf(c10[r] + bias1_0, 0.f);
                h1N[(16 + row) * H_STRIDE + (nt0 + 1) * 16 + ln15] = (bf16)fmaxf(c11[r] + bias1_1, 0.f);
            }
        }
        __syncthreads();
        #pragma unroll 1
        for (int nd = 0; nd < 2; ++nd) {
            const bf16* h1N = h1 + nd * KN * H_STRIDE;
            f32x4 d00 = {0.f,0.f,0.f,0.f}, d01 = d00, d10 = d00, d11 = d00;
            #pragma unroll
            for (int kt = 0; kt < 4; ++kt) {
                bf16x8 a0 = *(const bf16x8*)(h1N + ln15 * H_STRIDE + kt * 32 + quad * 8);
                bf16x8 a1 = *(const bf16x8*)(h1N + (16 + ln15) * H_STRIDE + kt * 32 + quad * 8);
                d00 = MFMA(a0, w2r[0][kt], d00);
                d01 = MFMA(a0, w2r[1][kt], d01);
                d10 = MFMA(a1, w2r[0][kt], d10);
                d11 = MFMA(a1, w2r[1][kt], d11);
            }
            #pragma unroll
            for (int r = 0; r < 4; ++r) {
                float p0 = w3_0 * fmaxf(d00[r] + bias2_0, 0.f)
                         + w3_1 * fmaxf(d01[r] + bias2_1, 0.f);
                float p1 = w3_0 * fmaxf(d10[r] + bias2_0, 0.f)
                         + w3_1 * fmaxf(d11[r] + bias2_1, 0.f);
                #pragma unroll
                for (int o = 1; o < 16; o <<= 1) {
                    p0 += __shfl_xor(p0, o);
                    p1 += __shfl_xor(p1, o);
                }
                if (ln15 == 0) {
                    lpart[nd][wave * KN + quad * 4 + r]      = p0;
                    lpart[nd][wave * KN + 16 + quad * 4 + r] = p1;
                }
            }
        }
        __syncthreads();
        if (wave < 2) {
            int nd = wave, k = lane & 31;
            float lg = lpart[nd][k] + lpart[nd][KN + k] + lpart[nd][2 * KN + k]
                     + lpart[nd][3 * KN + k] + b3v;
            int len = nd ? lenB : lenA;
            bool act = (lane < 32) && (k < len);
            float l = act ? lg : -1e30f;
            float m = l;
            #pragma unroll
            for (int o = 1; o < 32; o <<= 1) m = fmaxf(m, __shfl_xor(m, o));
            float e = act ? expf(l - m) : 0.f;
            float s = e;
            #pragma unroll
            for (int o = 1; o < 32; o <<= 1) s += __shfl_xor(s, o);
            if (lane < 32) att_s[nd][k] = (s > 0.f) ? (e / s) : 0.f;
        }
        __syncthreads();
        {
            int nd = t >> 7, d = t & 127;
            const float* euN = eu + nd * FB_EU_NODE_DW;
            float acc = 0.f;
            #pragma unroll
            for (int k = 0; k < KN; ++k)
                acc += att_s[nd][k] * euN[(k & 15) * FB_CHUNK_DW + ((k >> 4) << 7) + d];
            float sf = self_f[nd * D + d];
            int len = nd ? lenB : lenA;
            out[(size_t)(nA + nd) * D + d] = (len > 0) ? 0.5f * (acc + sf) : sf;
        }
        __syncthreads();
    }
}

extern "C" void kernel_launch(void* const* d_in, const int* in_sizes, int n_in,
                              void* d_out, int out_size, void* d_ws, size_t ws_size,
                              hipStream_t stream) {
    const int*   nodes     = (const int*)d_in[0];
    const int*   neigh_idx = (const int*)d_in[1];
    const int*   neigh_len = (const int*)d_in[2];
    const float* u2e       = (const float*)d_in[3];
    const float* W1        = (const float*)d_in[4];
    const float* b1        = (const float*)d_in[5];
    const float* W2        = (const float*)d_in[6];
    const float* b2        = (const float*)d_in[7];
    const float* W3        = (const float*)d_in[8];
    const float* b3        = (const float*)d_in[9];
    float* out = (float*)d_out;

    bf16* w1p = (bf16*)d_ws;                         // 65536 B
    bf16* w2p = w1p + 32768;                         // 32768 B
    bf16* u2e_bf = (bf16*)((char*)d_ws + 98304);     // 25.6 MB
    const size_t need = 98304ull + (size_t)VOCAB * D * 2;

    pack_weights_kernel<<<192, 256, 0, stream>>>(W1, W2, w1p, w2p);
    if (ws_size >= need) {
        convert_table_kernel<<<VOCAB * D / 2048, 256, 0, stream>>>(u2e, u2e_bf);
        graphrec_agg_kernel<<<GRID, 256, 0, stream>>>(nodes, neigh_idx, neigh_len,
                                                      u2e, u2e_bf, b1, b2, W3, b3,
                                                      w1p, w2p, out);
    } else {
        graphrec_agg_fb<<<GRID, 256, 0, stream>>>(nodes, neigh_idx, neigh_len, u2e,
                                                  b1, b2, W3, b3, w1p, w2p, out);
    }
}

// Round 6
// 259.647 us; speedup vs baseline: 1.0363x; 1.0363x over previous
//
#include <hip/hip_runtime.h>
#include <hip/hip_bf16.h>
#include <stdint.h>

#define KN 32
#define D  128
#define NNODES 20000
#define GRID 2500
#define ITERS 4            // 2 nodes/iter * 4 iters * 2500 blocks = 20000
#define VOCAB 100000

typedef __bf16 bf16;
typedef __bf16 bf16x8 __attribute__((ext_vector_type(8)));
typedef float  f32x4  __attribute__((ext_vector_type(4)));

// bf16 e_u LDS layout: 8 chunks/node; chunk c (1024 B, one GL2LDS) holds rows
// {c, c+8, c+16, c+24} (256 B each) + 16 B pad -> 520 bf16 elems per chunk.
// Row r -> elem (r&7)*520 + (r>>3)*128.
#define CHUNK_E 520
#define EU_NODE_E (8 * CHUNK_E)      // 4160 bf16 per node
#define H_STRIDE 136                 // bf16 elems; 68 dw, %32=4

#define GL2LDS(src, dst) __builtin_amdgcn_global_load_lds(                 \
    (const __attribute__((address_space(1))) void*)(src),                  \
    (__attribute__((address_space(3))) void*)(dst), 16, 0, 0)

#define MFMA(a, b, c) __builtin_amdgcn_mfma_f32_16x16x32_bf16((a), (b), (c), 0, 0, 0)

// ---------------------------------------------------------------------------
// Pack W1/W2 fp32 -> bf16 MFMA B-fragment order (lane holds B[k=quad*8+j][n=lane&15]).
// ---------------------------------------------------------------------------
__global__ __launch_bounds__(256) void pack_weights_kernel(
    const float* __restrict__ W1, const float* __restrict__ W2,
    bf16* __restrict__ w1p, bf16* __restrict__ w2p)
{
    int t = blockIdx.x * 256 + threadIdx.x;
    if (t < 32768) {
        int j = t & 7, lane = (t >> 3) & 63, kt = (t >> 9) & 7, nt = t >> 12;
        int d = nt * 16 + (lane & 15);
        int f = kt * 32 + ((lane >> 4) << 3) + j;
        w1p[t] = (bf16)W1[d * 256 + f];
    } else if (t < 49152) {
        int u = t - 32768;
        int j = u & 7, lane = (u >> 3) & 63, kt = (u >> 9) & 3, nt = u >> 11;
        int e  = nt * 16 + (lane & 15);
        int dd = kt * 32 + ((lane >> 4) << 3) + j;
        w2p[u] = (bf16)W2[e * 128 + dd];
    }
}

// u2e fp32 -> bf16 row-major table (12.8M elems, 8/thread, 6250 blocks exact).
__global__ __launch_bounds__(256) void convert_table_kernel(
    const float* __restrict__ u2e, bf16* __restrict__ tbl)
{
    size_t i = ((size_t)blockIdx.x * 256 + threadIdx.x) * 8;
    float4 a = *(const float4*)(u2e + i);
    float4 b = *(const float4*)(u2e + i + 4);
    bf16x8 v;
    v[0]=(bf16)a.x; v[1]=(bf16)a.y; v[2]=(bf16)a.z; v[3]=(bf16)a.w;
    v[4]=(bf16)b.x; v[5]=(bf16)b.y; v[6]=(bf16)b.z; v[7]=(bf16)b.w;
    *(bf16x8*)(tbl + i) = v;
}

// ---------------------------------------------------------------------------
// Fast path: 512 threads = 8 waves; wave w owns N-tile w (48 weight VGPRs).
// 2 nodes/iter, 8 nodes/block. launch_bounds(512,4): cap 128 VGPR -> no spill,
// 2 blocks/CU = 16 waves/CU (~50% occupancy) to hide the gather drain.
// ---------------------------------------------------------------------------
__global__ __launch_bounds__(512, 4) void graphrec_agg_kernel(
    const int*   __restrict__ nodes,
    const int*   __restrict__ neigh_idx,
    const int*   __restrict__ neigh_len,
    const float* __restrict__ u2e,
    const bf16*  __restrict__ u2e_bf,
    const float* __restrict__ b1,
    const float* __restrict__ b2,
    const float* __restrict__ W3,
    const float* __restrict__ b3,
    const bf16*  __restrict__ w1p,
    const bf16*  __restrict__ w2p,
    float*       __restrict__ out)
{
    __shared__ alignas(16) bf16  eu[2 * EU_NODE_E];     // 16640 B
    __shared__ alignas(16) float self_f[2 * D];         // 1024 B (A||B)
    __shared__ alignas(16) bf16  h1[2 * KN * H_STRIDE]; // 17408 B
    __shared__ float lpart[2][8 * KN];                  // 2048 B (8 wave partials)
    __shared__ float att_s[2][KN];                      // 256 B

    const int t    = threadIdx.x;
    const int lane = t & 63;
    const int wave = t >> 6;        // 0..7, owns N-tile `wave`
    const int ln15 = lane & 15;
    const int quad = lane >> 4;
    const int nt   = wave;

    const float bias1 = b1[nt * 16 + ln15];
    const float bias2 = b2[nt * 16 + ln15];
    const float w3v   = W3[nt * 16 + ln15];
    const float b3v   = b3[0];

    // resident weight fragments: 48 VGPRs
    bf16x8 w1r[8];
    #pragma unroll
    for (int ft = 0; ft < 8; ++ft)
        w1r[ft] = *(const bf16x8*)(w1p + (nt * 8 + ft) * 512 + lane * 8);
    bf16x8 w2r[4];
    #pragma unroll
    for (int kt = 0; kt < 4; ++kt)
        w2r[kt] = *(const bf16x8*)(w2p + (nt * 4 + kt) * 512 + lane * 8);

    #pragma unroll 1
    for (int it = 0; it < ITERS; ++it) {
        const int nA   = blockIdx.x * 8 + it * 2;
        const int lenA = neigh_len[nA];
        const int lenB = neigh_len[nA + 1];

        // ---- async gather: bf16 e_u direct to LDS (2 chunks per wave) ----
        {
            const int gnd = wave >> 2;            // node this wave stages
            const int cb  = (wave & 3) * 2;       // first of its 2 chunks
            #pragma unroll
            for (int j = 0; j < 2; ++j) {
                int chunk = cb + j;
                int idx = neigh_idx[(nA + gnd) * KN + chunk + ((lane >> 4) << 3)];
                GL2LDS(u2e_bf + (size_t)idx * D + ((lane & 15) << 3),
                       eu + gnd * EU_NODE_E + chunk * CHUNK_E);
            }
            if (wave == 0) {                      // selfA (512 B) || selfB (512 B), fp32
                int sidx = nodes[nA + (lane >> 5)];
                GL2LDS(u2e + (size_t)sidx * D + ((lane & 31) << 2), self_f);
            }
        }
        __syncthreads();   // barrier 1: gather resident (vmcnt drain)

        // ---- layer 1, both nodes: rows [32] x K [256] -> N-tile `nt` ----
        #pragma unroll 1
        for (int nd = 0; nd < 2; ++nd) {
            const bf16*  euN = eu + nd * EU_NODE_E;
            const float* sfN = self_f + nd * D;
            bf16* h1N = h1 + nd * KN * H_STRIDE;

            f32x4 c0 = {0.f,0.f,0.f,0.f}, c1 = c0;
            const int rb = (ln15 & 7) * CHUNK_E + (ln15 >> 3) * 128;
            #pragma unroll
            for (int ft = 0; ft < 4; ++ft) {
                bf16x8 a0 = *(const bf16x8*)(euN + rb + ft * 32 + quad * 8);
                bf16x8 a1 = *(const bf16x8*)(euN + rb + 256 + ft * 32 + quad * 8);
                c0 = MFMA(a0, w1r[ft], c0);
                c1 = MFMA(a1, w1r[ft], c1);
            }
            #pragma unroll
            for (int ft = 4; ft < 8; ++ft) {   // self half: same A both row-tiles
                int off = (ft - 4) * 32 + quad * 8;
                f32x4 u0 = *(const f32x4*)(sfN + off);
                f32x4 u1 = *(const f32x4*)(sfN + off + 4);
                bf16x8 a;
                #pragma unroll
                for (int e = 0; e < 4; ++e) { a[e] = (bf16)u0[e]; a[4 + e] = (bf16)u1[e]; }
                c0 = MFMA(a, w1r[ft], c0);
                c1 = MFMA(a, w1r[ft], c1);
            }
            #pragma unroll
            for (int r = 0; r < 4; ++r) {      // relu+bias -> bf16 LDS
                int row = quad * 4 + r;
                h1N[row * H_STRIDE + nt * 16 + ln15]        = (bf16)fmaxf(c0[r] + bias1, 0.f);
                h1N[(16 + row) * H_STRIDE + nt * 16 + ln15] = (bf16)fmaxf(c1[r] + bias1, 0.f);
            }
        }
        __syncthreads();   // barrier 2

        // ---- layer 2 + fused logits, both nodes ----
        #pragma unroll 1
        for (int nd = 0; nd < 2; ++nd) {
            const bf16* h1N = h1 + nd * KN * H_STRIDE;
            f32x4 d0 = {0.f,0.f,0.f,0.f}, d1 = d0;
            #pragma unroll
            for (int kt = 0; kt < 4; ++kt) {
                bf16x8 a0 = *(const bf16x8*)(h1N + ln15 * H_STRIDE + kt * 32 + quad * 8);
                bf16x8 a1 = *(const bf16x8*)(h1N + (16 + ln15) * H_STRIDE + kt * 32 + quad * 8);
                d0 = MFMA(a0, w2r[kt], d0);
                d1 = MFMA(a1, w2r[kt], d1);
            }
            #pragma unroll
            for (int r = 0; r < 4; ++r) {   // h2 never materialized
                float p0 = w3v * fmaxf(d0[r] + bias2, 0.f);
                float p1 = w3v * fmaxf(d1[r] + bias2, 0.f);
                #pragma unroll
                for (int o = 1; o < 16; o <<= 1) {   // reduce over ln15 within quad
                    p0 += __shfl_xor(p0, o);
                    p1 += __shfl_xor(p1, o);
                }
                if (ln15 == 0) {
                    lpart[nd][wave * KN + quad * 4 + r]      = p0;
                    lpart[nd][wave * KN + 16 + quad * 4 + r] = p1;
                }
            }
        }
        __syncthreads();   // barrier 3

        // ---- masked softmax: wave 0 -> node A, wave 1 -> node B ----
        if (wave < 2) {
            int nd = wave, k = lane & 31;
            float lg = b3v;
            #pragma unroll
            for (int j = 0; j < 8; ++j) lg += lpart[nd][j * KN + k];
            int len = nd ? lenB : lenA;
            bool act = (lane < 32) && (k < len);
            float l = act ? lg : -1e30f;
            float m = l;
            #pragma unroll
            for (int o = 1; o < 32; o <<= 1) m = fmaxf(m, __shfl_xor(m, o));
            float e = act ? expf(l - m) : 0.f;
            float s = e;
            #pragma unroll
            for (int o = 1; o < 32; o <<= 1) s += __shfl_xor(s, o);
            if (lane < 32) att_s[nd][k] = (s > 0.f) ? (e / s) : 0.f;
        }
        __syncthreads();   // barrier 4

        // ---- aggregation: threads 0..255 (t<128 node A, else node B) ----
        if (t < 256) {
            int nd = t >> 7, d = t & 127;
            const bf16* euN = eu + nd * EU_NODE_E;
            float acc = 0.f;
            #pragma unroll
            for (int k = 0; k < KN; ++k)
                acc += att_s[nd][k] * (float)euN[(k & 7) * CHUNK_E + (k >> 3) * 128 + d];
            float sf = self_f[nd * D + d];
            int len = nd ? lenB : lenA;
            out[(size_t)(nA + nd) * D + d] = (len > 0) ? 0.5f * (acc + sf) : sf;
        }
        __syncthreads();   // barrier 5: protect LDS for next iteration
    }
}

// ---------------------------------------------------------------------------
// Fallback (round-4 kernel, fp32 gather, 256 threads) for small ws_size.
// ---------------------------------------------------------------------------
#define FB_CHUNK_DW 260
#define FB_EU_NODE_DW (16 * FB_CHUNK_DW)

__global__ __launch_bounds__(256, 3) void graphrec_agg_fb(
    const int*   __restrict__ nodes,
    const int*   __restrict__ neigh_idx,
    const int*   __restrict__ neigh_len,
    const float* __restrict__ u2e,
    const float* __restrict__ b1,
    const float* __restrict__ b2,
    const float* __restrict__ W3,
    const float* __restrict__ b3,
    const bf16*  __restrict__ w1p,
    const bf16*  __restrict__ w2p,
    float*       __restrict__ out)
{
    __shared__ alignas(16) float eu[2 * FB_EU_NODE_DW];
    __shared__ alignas(16) bf16  h1[2 * KN * H_STRIDE];
    __shared__ alignas(16) float self_f[2 * D];
    __shared__ float lpart[2][4 * KN];
    __shared__ float att_s[2][KN];

    const int t    = threadIdx.x;
    const int lane = t & 63;
    const int wave = t >> 6;
    const int ln15 = lane & 15;
    const int quad = lane >> 4;
    const int nt0  = wave * 2;

    const float bias1_0 = b1[nt0 * 16 + ln15];
    const float bias1_1 = b1[(nt0 + 1) * 16 + ln15];
    const float bias2_0 = b2[nt0 * 16 + ln15];
    const float bias2_1 = b2[(nt0 + 1) * 16 + ln15];
    const float w3_0    = W3[nt0 * 16 + ln15];
    const float w3_1    = W3[(nt0 + 1) * 16 + ln15];
    const float b3v     = b3[0];

    bf16x8 w1r[2][8];
    #pragma unroll
    for (int nt = 0; nt < 2; ++nt)
        #pragma unroll
        for (int ft = 0; ft < 8; ++ft)
            w1r[nt][ft] = *(const bf16x8*)(w1p + ((nt0 + nt) * 8 + ft) * 512 + lane * 8);
    bf16x8 w2r[2][4];
    #pragma unroll
    for (int nt = 0; nt < 2; ++nt)
        #pragma unroll
        for (int kt = 0; kt < 4; ++kt)
            w2r[nt][kt] = *(const bf16x8*)(w2p + ((nt0 + nt) * 4 + kt) * 512 + lane * 8);

    #pragma unroll 1
    for (int it = 0; it < ITERS; ++it) {
        const int nA   = blockIdx.x * 8 + it * 2;
        const int lenA = neigh_len[nA];
        const int lenB = neigh_len[nA + 1];
        {
            const int half = lane >> 5;
            const int colb = (lane & 31) << 4;
            #pragma unroll
            for (int nd = 0; nd < 2; ++nd) {
                #pragma unroll
                for (int j = 0; j < 4; ++j) {
                    int chunk = wave * 4 + j;
                    int idx = neigh_idx[(nA + nd) * KN + chunk + (half << 4)];
                    const char* src = (const char*)(u2e + (size_t)idx * D) + colb;
                    GL2LDS(src, eu + nd * FB_EU_NODE_DW + chunk * FB_CHUNK_DW);
                }
            }
            if (wave == 0) {
                int sidx = nodes[nA + half];
                const char* src = (const char*)(u2e + (size_t)sidx * D) + colb;
                GL2LDS(src, self_f);
            }
        }
        __syncthreads();
        #pragma unroll 1
        for (int nd = 0; nd < 2; ++nd) {
            const float* euN = eu + nd * FB_EU_NODE_DW;
            const float* sfN = self_f + nd * D;
            bf16* h1N = h1 + nd * KN * H_STRIDE;
            f32x4 c00 = {0.f,0.f,0.f,0.f}, c01 = c00, c10 = c00, c11 = c00;
            const int r0 = ln15 * FB_CHUNK_DW;
            #pragma unroll
            for (int ft = 0; ft < 4; ++ft) {
                int off = ft * 32 + quad * 8;
                f32x4 u0 = *(const f32x4*)(euN + r0 + off);
                f32x4 u1 = *(const f32x4*)(euN + r0 + off + 4);
                f32x4 v0 = *(const f32x4*)(euN + r0 + 128 + off);
                f32x4 v1 = *(const f32x4*)(euN + r0 + 128 + off + 4);
                bf16x8 a0, a1;
                #pragma unroll
                for (int e = 0; e < 4; ++e) {
                    a0[e] = (bf16)u0[e]; a0[4 + e] = (bf16)u1[e];
                    a1[e] = (bf16)v0[e]; a1[4 + e] = (bf16)v1[e];
                }
                c00 = MFMA(a0, w1r[0][ft], c00);
                c01 = MFMA(a0, w1r[1][ft], c01);
                c10 = MFMA(a1, w1r[0][ft], c10);
                c11 = MFMA(a1, w1r[1][ft], c11);
            }
            #pragma unroll
            for (int ft = 4; ft < 8; ++ft) {
                int off = (ft - 4) * 32 + quad * 8;
                f32x4 u0 = *(const f32x4*)(sfN + off);
                f32x4 u1 = *(const f32x4*)(sfN + off + 4);
                bf16x8 a;
                #pragma unroll
                for (int e = 0; e < 4; ++e) { a[e] = (bf16)u0[e]; a[4 + e] = (bf16)u1[e]; }
                c00 = MFMA(a, w1r[0][ft], c00);
                c01 = MFMA(a, w1r[1][ft], c01);
                c10 = MFMA(a, w1r[0][ft], c10);
                c11 = MFMA(a, w1r[1][ft], c11);
            }
            #pragma unroll
            for (int r = 0; r < 4; ++r) {
                int row = quad * 4 + r;
                h1N[row * H_STRIDE + nt0 * 16 + ln15]              = (bf16)fmaxf(c00[r] + bias1_0, 0.f);
                h1N[row * H_STRIDE + (nt0 + 1) * 16 + ln15]        = (bf16)fmaxf(c01[r] + bias1_1, 0.f);
                h1N[(16 + row) * H_STRIDE + nt0 * 16 + ln15]       = (bf16)fmaxf(c10[r] + bias1_0, 0.f);
                h1N[(16 + row) * H_STRIDE + (nt0 + 1) * 16 + ln15] = (bf16)fmaxf(c11[r] + bias1_1, 0.f);
            }
        }
        __syncthreads();
        #pragma unroll 1
        for (int nd = 0; nd < 2; ++nd) {
            const bf16* h1N = h1 + nd * KN * H_STRIDE;
            f32x4 d00 = {0.f,0.f,0.f,0.f}, d01 = d00, d10 = d00, d11 = d00;
            #pragma unroll
            for (int kt = 0; kt < 4; ++kt) {
                bf16x8 a0 = *(const bf16x8*)(h1N + ln15 * H_STRIDE + kt * 32 + quad * 8);
                bf16x8 a1 = *(const bf16x8*)(h1N + (16 + ln15) * H_STRIDE + kt * 32 + quad * 8);
                d00 = MFMA(a0, w2r[0][kt], d00);
                d01 = MFMA(a0, w2r[1][kt], d01);
                d10 = MFMA(a1, w2r[0][kt], d10);
                d11 = MFMA(a1, w2r[1][kt], d11);
            }
            #pragma unroll
            for (int r = 0; r < 4; ++r) {
                float p0 = w3_0 * fmaxf(d00[r] + bias2_0, 0.f)
                         + w3_1 * fmaxf(d01[r] + bias2_1, 0.f);
                float p1 = w3_0 * fmaxf(d10[r] + bias2_0, 0.f)
                         + w3_1 * fmaxf(d11[r] + bias2_1, 0.f);
                #pragma unroll
                for (int o = 1; o < 16; o <<= 1) {
                    p0 += __shfl_xor(p0, o);
                    p1 += __shfl_xor(p1, o);
                }
                if (ln15 == 0) {
                    lpart[nd][wave * KN + quad * 4 + r]      = p0;
                    lpart[nd][wave * KN + 16 + quad * 4 + r] = p1;
                }
            }
        }
        __syncthreads();
        if (wave < 2) {
            int nd = wave, k = lane & 31;
            float lg = lpart[nd][k] + lpart[nd][KN + k] + lpart[nd][2 * KN + k]
                     + lpart[nd][3 * KN + k] + b3v;
            int len = nd ? lenB : lenA;
            bool act = (lane < 32) && (k < len);
            float l = act ? lg : -1e30f;
            float m = l;
            #pragma unroll
            for (int o = 1; o < 32; o <<= 1) m = fmaxf(m, __shfl_xor(m, o));
            float e = act ? expf(l - m) : 0.f;
            float s = e;
            #pragma unroll
            for (int o = 1; o < 32; o <<= 1) s += __shfl_xor(s, o);
            if (lane < 32) att_s[nd][k] = (s > 0.f) ? (e / s) : 0.f;
        }
        __syncthreads();
        {
            int nd = t >> 7, d = t & 127;
            const float* euN = eu + nd * FB_EU_NODE_DW;
            float acc = 0.f;
            #pragma unroll
            for (int k = 0; k < KN; ++k)
                acc += att_s[nd][k] * euN[(k & 15) * FB_CHUNK_DW + ((k >> 4) << 7) + d];
            float sf = self_f[nd * D + d];
            int len = nd ? lenB : lenA;
            out[(size_t)(nA + nd) * D + d] = (len > 0) ? 0.5f * (acc + sf) : sf;
        }
        __syncthreads();
    }
}

extern "C" void kernel_launch(void* const* d_in, const int* in_sizes, int n_in,
                              void* d_out, int out_size, void* d_ws, size_t ws_size,
                              hipStream_t stream) {
    const int*   nodes     = (const int*)d_in[0];
    const int*   neigh_idx = (const int*)d_in[1];
    const int*   neigh_len = (const int*)d_in[2];
    const float* u2e       = (const float*)d_in[3];
    const float* W1        = (const float*)d_in[4];
    const float* b1        = (const float*)d_in[5];
    const float* W2        = (const float*)d_in[6];
    const float* b2        = (const float*)d_in[7];
    const float* W3        = (const float*)d_in[8];
    const float* b3        = (const float*)d_in[9];
    float* out = (float*)d_out;

    bf16* w1p = (bf16*)d_ws;                         // 65536 B
    bf16* w2p = w1p + 32768;                         // 32768 B
    bf16* u2e_bf = (bf16*)((char*)d_ws + 98304);     // 25.6 MB
    const size_t need = 98304ull + (size_t)VOCAB * D * 2;

    pack_weights_kernel<<<192, 256, 0, stream>>>(W1, W2, w1p, w2p);
    if (ws_size >= need) {
        convert_table_kernel<<<VOCAB * D / 2048, 256, 0, stream>>>(u2e, u2e_bf);
        graphrec_agg_kernel<<<GRID, 512, 0, stream>>>(nodes, neigh_idx, neigh_len,
                                                      u2e, u2e_bf, b1, b2, W3, b3,
                                                      w1p, w2p, out);
    } else {
        graphrec_agg_fb<<<GRID, 256, 0, stream>>>(nodes, neigh_idx, neigh_len, u2e,
                                                  b1, b2, W3, b3, w1p, w2p, out);
    }
}

// Round 7
// 215.916 us; speedup vs baseline: 1.2462x; 1.2025x over previous
//
#include <hip/hip_runtime.h>
#include <hip/hip_bf16.h>
#include <stdint.h>

#define KN 32
#define D  128
#define NNODES 20000
#define GRID 2500
#define ITERS 4            // 2 nodes/iter * 4 iters * 2500 blocks = 20000
#define VOCAB 100000
#define SV1_BLOCKS ((NNODES + 127) / 128)

typedef __bf16 bf16;
typedef __bf16 bf16x8 __attribute__((ext_vector_type(8)));
typedef float  f32x4  __attribute__((ext_vector_type(4)));

// bf16 e_u LDS layout: 8 chunks/node; chunk c (1024 B, one GL2LDS) holds rows
// {c, c+8, c+16, c+24} (256 B each) + 16 B pad -> 520 bf16 elems per chunk.
// Row r -> elem (r&7)*520 + (r>>3)*128.
#define CHUNK_E 520
#define EU_NODE_E (8 * CHUNK_E)      // 4160 bf16 per node
#define H_STRIDE 136                 // bf16 elems; 68 dw, %32=4

#define GL2LDS(src, dst) __builtin_amdgcn_global_load_lds(                 \
    (const __attribute__((address_space(1))) void*)(src),                  \
    (__attribute__((address_space(3))) void*)(dst), 16, 0, 0)

#define MFMA(a, b, c) __builtin_amdgcn_mfma_f32_16x16x32_bf16((a), (b), (c), 0, 0, 0)

// ---------------------------------------------------------------------------
// Pack W1 (128x256) and W2 (128x128) fp32 -> bf16 in MFMA B-fragment order.
// B-frag for mfma_f32_16x16x32_bf16: lane holds B[k=quad*8+j][n=lane&15].
// w1p fts 0..3 = e_u half (f in [0,128)), fts 4..7 = self half (f in [128,256)).
// ---------------------------------------------------------------------------
__global__ __launch_bounds__(256) void pack_weights_kernel(
    const float* __restrict__ W1, const float* __restrict__ W2,
    bf16* __restrict__ w1p, bf16* __restrict__ w2p)
{
    int t = blockIdx.x * 256 + threadIdx.x;
    if (t < 32768) {
        int j = t & 7, lane = (t >> 3) & 63, kt = (t >> 9) & 7, nt = t >> 12;
        int d = nt * 16 + (lane & 15);
        int f = kt * 32 + ((lane >> 4) << 3) + j;
        w1p[t] = (bf16)W1[d * 256 + f];
    } else if (t < 49152) {
        int u = t - 32768;
        int j = u & 7, lane = (u >> 3) & 63, kt = (u >> 9) & 3, nt = u >> 11;
        int e  = nt * 16 + (lane & 15);
        int dd = kt * 32 + ((lane >> 4) << 3) + j;
        w2p[u] = (bf16)W2[e * 128 + dd];
    }
}

// u2e fp32 -> bf16 row-major table (12.8M elems, 8/thread, 6250 blocks exact).
__global__ __launch_bounds__(256) void convert_table_kernel(
    const float* __restrict__ u2e, bf16* __restrict__ tbl)
{
    size_t i = ((size_t)blockIdx.x * 256 + threadIdx.x) * 8;
    float4 a = *(const float4*)(u2e + i);
    float4 b = *(const float4*)(u2e + i + 4);
    bf16x8 v;
    v[0]=(bf16)a.x; v[1]=(bf16)a.y; v[2]=(bf16)a.z; v[3]=(bf16)a.w;
    v[4]=(bf16)b.x; v[5]=(bf16)b.y; v[6]=(bf16)b.z; v[7]=(bf16)b.w;
    *(bf16x8*)(tbl + i) = v;
}

// ---------------------------------------------------------------------------
// sv1[n][d] = sum_f self_feats[n][f] * W1[d][128+f]  (the rank-1 self half of
// layer 1, hoisted out of the per-neighbor MLP). 128 node-rows per block.
// ---------------------------------------------------------------------------
__global__ __launch_bounds__(256) void sv1_kernel(
    const int*  __restrict__ nodes,
    const bf16* __restrict__ u2e_bf,
    const bf16* __restrict__ w1p,
    float*      __restrict__ sv1t)
{
    __shared__ alignas(16) bf16 sr[4 * EU_NODE_E];   // 33280 B

    const int t    = threadIdx.x;
    const int lane = t & 63;
    const int wave = t >> 6;
    const int ln15 = lane & 15;
    const int quad = lane >> 4;
    const int r0   = blockIdx.x * 128;

    // stage: wave w gathers its 32-row group (8 chunks)
    #pragma unroll
    for (int c = 0; c < 8; ++c) {
        int grow = r0 + wave * 32 + c + ((lane >> 4) << 3);
        int node = nodes[grow < NNODES ? grow : NNODES - 1];
        GL2LDS(u2e_bf + (size_t)node * D + ((lane & 15) << 3),
               sr + wave * EU_NODE_E + c * CHUNK_E);
    }
    __syncthreads();

    const bf16* g  = sr + wave * EU_NODE_E;
    const int   rb = (ln15 & 7) * CHUNK_E + (ln15 >> 3) * 128;

    #pragma unroll 1
    for (int np = 0; np < 4; ++np) {
        int nt0 = np * 2;
        bf16x8 b0[4], b1[4];
        #pragma unroll
        for (int kt = 0; kt < 4; ++kt) {   // self-half B-frags: fts 4..7
            b0[kt] = *(const bf16x8*)(w1p + (nt0 * 8 + 4 + kt) * 512 + lane * 8);
            b1[kt] = *(const bf16x8*)(w1p + ((nt0 + 1) * 8 + 4 + kt) * 512 + lane * 8);
        }
        f32x4 c00 = {0.f,0.f,0.f,0.f}, c01 = c00, c10 = c00, c11 = c00;
        #pragma unroll
        for (int kt = 0; kt < 4; ++kt) {
            bf16x8 a0 = *(const bf16x8*)(g + rb + kt * 32 + quad * 8);
            bf16x8 a1 = *(const bf16x8*)(g + rb + 256 + kt * 32 + quad * 8);
            c00 = MFMA(a0, b0[kt], c00);
            c01 = MFMA(a0, b1[kt], c01);
            c10 = MFMA(a1, b0[kt], c10);
            c11 = MFMA(a1, b1[kt], c11);
        }
        #pragma unroll
        for (int r = 0; r < 4; ++r) {
            int row = quad * 4 + r;
            int gr0 = r0 + wave * 32 + row;
            int gr1 = gr0 + 16;
            if (gr0 < NNODES) {
                sv1t[(size_t)gr0 * D + nt0 * 16 + ln15]       = c00[r];
                sv1t[(size_t)gr0 * D + (nt0 + 1) * 16 + ln15] = c01[r];
            }
            if (gr1 < NNODES) {
                sv1t[(size_t)gr1 * D + nt0 * 16 + ln15]       = c10[r];
                sv1t[(size_t)gr1 * D + (nt0 + 1) * 16 + ln15] = c11[r];
            }
        }
    }
}

// ---------------------------------------------------------------------------
// Main kernel: 256 threads = 4 waves, each owns 2 N-tiles (64 weight VGPRs:
// W1 e_u-half only + W2). 2 nodes/iter, 8 nodes/block. launch_bounds(256,4):
// 4 blocks/CU = 16 waves/CU. Layer-1 self half comes in as bias row sv1[n].
// ---------------------------------------------------------------------------
__global__ __launch_bounds__(256, 4) void graphrec_agg_kernel(
    const int*   __restrict__ nodes,
    const int*   __restrict__ neigh_idx,
    const int*   __restrict__ neigh_len,
    const float* __restrict__ u2e,
    const bf16*  __restrict__ u2e_bf,
    const float* __restrict__ sv1t,
    const float* __restrict__ b1,
    const float* __restrict__ b2,
    const float* __restrict__ W3,
    const float* __restrict__ b3,
    const bf16*  __restrict__ w1p,
    const bf16*  __restrict__ w2p,
    float*       __restrict__ out)
{
    __shared__ alignas(16) bf16  eu[2 * EU_NODE_E];     // 16640 B
    __shared__ alignas(16) float self_f[2 * D];         // 1024 B (A||B)
    __shared__ alignas(16) bf16  h1[2 * KN * H_STRIDE]; // 17408 B
    __shared__ float lpart[2][4 * KN];                  // 1024 B

    const int t    = threadIdx.x;
    const int lane = t & 63;
    const int wave = t >> 6;
    const int ln15 = lane & 15;
    const int quad = lane >> 4;
    const int nt0  = wave * 2;

    const float bias1_0 = b1[nt0 * 16 + ln15];
    const float bias1_1 = b1[(nt0 + 1) * 16 + ln15];
    const float bias2_0 = b2[nt0 * 16 + ln15];
    const float bias2_1 = b2[(nt0 + 1) * 16 + ln15];
    const float w3_0    = W3[nt0 * 16 + ln15];
    const float w3_1    = W3[(nt0 + 1) * 16 + ln15];
    const float b3v     = b3[0];

    // resident weight fragments: 64 VGPRs (W1 e_u half + W2)
    bf16x8 w1r[2][4];
    #pragma unroll
    for (int nt = 0; nt < 2; ++nt)
        #pragma unroll
        for (int ft = 0; ft < 4; ++ft)
            w1r[nt][ft] = *(const bf16x8*)(w1p + ((nt0 + nt) * 8 + ft) * 512 + lane * 8);
    bf16x8 w2r[2][4];
    #pragma unroll
    for (int nt = 0; nt < 2; ++nt)
        #pragma unroll
        for (int kt = 0; kt < 4; ++kt)
            w2r[nt][kt] = *(const bf16x8*)(w2p + ((nt0 + nt) * 4 + kt) * 512 + lane * 8);

    #pragma unroll 1
    for (int it = 0; it < ITERS; ++it) {
        const int nA   = blockIdx.x * 8 + it * 2;
        const int lenA = neigh_len[nA];
        const int lenB = neigh_len[nA + 1];

        // per-node self-contribution bias rows (L3-hot scalar loads, issued early)
        const float svA0 = sv1t[(size_t)nA * D + nt0 * 16 + ln15];
        const float svA1 = sv1t[(size_t)nA * D + (nt0 + 1) * 16 + ln15];
        const float svB0 = sv1t[(size_t)(nA + 1) * D + nt0 * 16 + ln15];
        const float svB1 = sv1t[(size_t)(nA + 1) * D + (nt0 + 1) * 16 + ln15];

        // ---- async gather: bf16 e_u direct to LDS (4 chunks/wave) ----
        {
            const int gnd = wave >> 1;            // node this wave stages
            const int cb  = (wave & 1) * 4;       // first of its 4 chunks
            #pragma unroll
            for (int j = 0; j < 4; ++j) {
                int chunk = cb + j;
                int idx = neigh_idx[(nA + gnd) * KN + chunk + ((lane >> 4) << 3)];
                GL2LDS(u2e_bf + (size_t)idx * D + ((lane & 15) << 3),
                       eu + gnd * EU_NODE_E + chunk * CHUNK_E);
            }
            if (wave == 0) {                      // selfA||selfB fp32, ONE instr
                int sidx = nodes[nA + (lane >> 5)];
                GL2LDS(u2e + (size_t)sidx * D + ((lane & 31) << 2), self_f);
            }
        }
        __syncthreads();   // barrier 1: gather resident

        // ---- layer 1, both nodes: [32 x 128] @ [128 x 128] + sv1 bias ----
        #pragma unroll 1
        for (int nd = 0; nd < 2; ++nd) {
            const bf16* euN = eu + nd * EU_NODE_E;
            bf16* h1N = h1 + nd * KN * H_STRIDE;

            f32x4 c00 = {0.f,0.f,0.f,0.f}, c01 = c00, c10 = c00, c11 = c00;
            const int rb = (ln15 & 7) * CHUNK_E + (ln15 >> 3) * 128;
            #pragma unroll
            for (int ft = 0; ft < 4; ++ft) {
                bf16x8 a0 = *(const bf16x8*)(euN + rb + ft * 32 + quad * 8);
                bf16x8 a1 = *(const bf16x8*)(euN + rb + 256 + ft * 32 + quad * 8);
                c00 = MFMA(a0, w1r[0][ft], c00);
                c01 = MFMA(a0, w1r[1][ft], c01);
                c10 = MFMA(a1, w1r[0][ft], c10);
                c11 = MFMA(a1, w1r[1][ft], c11);
            }
            const float s0 = nd ? svB0 : svA0;
            const float s1 = nd ? svB1 : svA1;
            #pragma unroll
            for (int r = 0; r < 4; ++r) {      // relu(c + b1 + sv1) -> bf16 LDS
                int row = quad * 4 + r;
                h1N[row * H_STRIDE + nt0 * 16 + ln15]              = (bf16)fmaxf(c00[r] + bias1_0 + s0, 0.f);
                h1N[row * H_STRIDE + (nt0 + 1) * 16 + ln15]        = (bf16)fmaxf(c01[r] + bias1_1 + s1, 0.f);
                h1N[(16 + row) * H_STRIDE + nt0 * 16 + ln15]       = (bf16)fmaxf(c10[r] + bias1_0 + s0, 0.f);
                h1N[(16 + row) * H_STRIDE + (nt0 + 1) * 16 + ln15] = (bf16)fmaxf(c11[r] + bias1_1 + s1, 0.f);
            }
        }
        __syncthreads();   // barrier 2

        // ---- layer 2 + fused logits, both nodes ----
        #pragma unroll 1
        for (int nd = 0; nd < 2; ++nd) {
            const bf16* h1N = h1 + nd * KN * H_STRIDE;
            f32x4 d00 = {0.f,0.f,0.f,0.f}, d01 = d00, d10 = d00, d11 = d00;
            #pragma unroll
            for (int kt = 0; kt < 4; ++kt) {
                bf16x8 a0 = *(const bf16x8*)(h1N + ln15 * H_STRIDE + kt * 32 + quad * 8);
                bf16x8 a1 = *(const bf16x8*)(h1N + (16 + ln15) * H_STRIDE + kt * 32 + quad * 8);
                d00 = MFMA(a0, w2r[0][kt], d00);
                d01 = MFMA(a0, w2r[1][kt], d01);
                d10 = MFMA(a1, w2r[0][kt], d10);
                d11 = MFMA(a1, w2r[1][kt], d11);
            }
            #pragma unroll
            for (int r = 0; r < 4; ++r) {   // h2 never materialized
                float p0 = w3_0 * fmaxf(d00[r] + bias2_0, 0.f)
                         + w3_1 * fmaxf(d01[r] + bias2_1, 0.f);
                float p1 = w3_0 * fmaxf(d10[r] + bias2_0, 0.f)
                         + w3_1 * fmaxf(d11[r] + bias2_1, 0.f);
                #pragma unroll
                for (int o = 1; o < 16; o <<= 1) {
                    p0 += __shfl_xor(p0, o);
                    p1 += __shfl_xor(p1, o);
                }
                if (ln15 == 0) {
                    lpart[nd][wave * KN + quad * 4 + r]      = p0;
                    lpart[nd][wave * KN + 16 + quad * 4 + r] = p1;
                }
            }
        }
        __syncthreads();   // barrier 3

        // ---- per-wave softmax + aggregation (wave w: node w>>1, cols (w&1)*64..) ----
        {
            const int nd = wave >> 1;
            const int k  = lane & 31;
            float lg = lpart[nd][k] + lpart[nd][KN + k] + lpart[nd][2 * KN + k]
                     + lpart[nd][3 * KN + k] + b3v;
            const int len = nd ? lenB : lenA;
            bool act = k < len;
            float l = act ? lg : -1e30f;
            float m = l;
            #pragma unroll
            for (int o = 1; o < 32; o <<= 1) m = fmaxf(m, __shfl_xor(m, o));
            float e = act ? expf(l - m) : 0.f;
            float s = e;
            #pragma unroll
            for (int o = 1; o < 32; o <<= 1) s += __shfl_xor(s, o);
            float att = (s > 0.f) ? (e / s) : 0.f;

            const int d = ((wave & 1) << 6) + lane;   // wait: lane in [0,64) -> cols
            const bf16* euN = eu + nd * EU_NODE_E;
            float acc = 0.f;
            #pragma unroll
            for (int k2 = 0; k2 < KN; ++k2) {
                float a  = __shfl(att, k2);
                float ev = (float)euN[(k2 & 7) * CHUNK_E + (k2 >> 3) * 128 + (d & 127)];
                acc += a * ev;
            }
            float sf = self_f[nd * D + (d & 127)];
            out[(size_t)(nA + nd) * D + (d & 127)] = (len > 0) ? 0.5f * (acc + sf) : sf;
        }
        __syncthreads();   // barrier 4: protect LDS for next iteration
    }
}

// ---------------------------------------------------------------------------
// Fallback (round-4 kernel, fp32 gather, no sv1) for small ws_size.
// ---------------------------------------------------------------------------
#define FB_CHUNK_DW 260
#define FB_EU_NODE_DW (16 * FB_CHUNK_DW)

__global__ __launch_bounds__(256, 3) void graphrec_agg_fb(
    const int*   __restrict__ nodes,
    const int*   __restrict__ neigh_idx,
    const int*   __restrict__ neigh_len,
    const float* __restrict__ u2e,
    const float* __restrict__ b1,
    const float* __restrict__ b2,
    const float* __restrict__ W3,
    const float* __restrict__ b3,
    const bf16*  __restrict__ w1p,
    const bf16*  __restrict__ w2p,
    float*       __restrict__ out)
{
    __shared__ alignas(16) float eu[2 * FB_EU_NODE_DW];
    __shared__ alignas(16) bf16  h1[2 * KN * H_STRIDE];
    __shared__ alignas(16) float self_f[2 * D];
    __shared__ float lpart[2][4 * KN];
    __shared__ float att_s[2][KN];

    const int t    = threadIdx.x;
    const int lane = t & 63;
    const int wave = t >> 6;
    const int ln15 = lane & 15;
    const int quad = lane >> 4;
    const int nt0  = wave * 2;

    const float bias1_0 = b1[nt0 * 16 + ln15];
    const float bias1_1 = b1[(nt0 + 1) * 16 + ln15];
    const float bias2_0 = b2[nt0 * 16 + ln15];
    const float bias2_1 = b2[(nt0 + 1) * 16 + ln15];
    const float w3_0    = W3[nt0 * 16 + ln15];
    const float w3_1    = W3[(nt0 + 1) * 16 + ln15];
    const float b3v     = b3[0];

    bf16x8 w1r[2][8];
    #pragma unroll
    for (int nt = 0; nt < 2; ++nt)
        #pragma unroll
        for (int ft = 0; ft < 8; ++ft)
            w1r[nt][ft] = *(const bf16x8*)(w1p + ((nt0 + nt) * 8 + ft) * 512 + lane * 8);
    bf16x8 w2r[2][4];
    #pragma unroll
    for (int nt = 0; nt < 2; ++nt)
        #pragma unroll
        for (int kt = 0; kt < 4; ++kt)
            w2r[nt][kt] = *(const bf16x8*)(w2p + ((nt0 + nt) * 4 + kt) * 512 + lane * 8);

    #pragma unroll 1
    for (int it = 0; it < ITERS; ++it) {
        const int nA   = blockIdx.x * 8 + it * 2;
        const int lenA = neigh_len[nA];
        const int lenB = neigh_len[nA + 1];
        {
            const int half = lane >> 5;
            const int colb = (lane & 31) << 4;
            #pragma unroll
            for (int nd = 0; nd < 2; ++nd) {
                #pragma unroll
                for (int j = 0; j < 4; ++j) {
                    int chunk = wave * 4 + j;
                    int idx = neigh_idx[(nA + nd) * KN + chunk + (half << 4)];
                    const char* src = (const char*)(u2e + (size_t)idx * D) + colb;
                    GL2LDS(src, eu + nd * FB_EU_NODE_DW + chunk * FB_CHUNK_DW);
                }
            }
            if (wave == 0) {
                int sidx = nodes[nA + half];
                const char* src = (const char*)(u2e + (size_t)sidx * D) + colb;
                GL2LDS(src, self_f);
            }
        }
        __syncthreads();
        #pragma unroll 1
        for (int nd = 0; nd < 2; ++nd) {
            const float* euN = eu + nd * FB_EU_NODE_DW;
            const float* sfN = self_f + nd * D;
            bf16* h1N = h1 + nd * KN * H_STRIDE;
            f32x4 c00 = {0.f,0.f,0.f,0.f}, c01 = c00, c10 = c00, c11 = c00;
            const int r0 = ln15 * FB_CHUNK_DW;
            #pragma unroll
            for (int ft = 0; ft < 4; ++ft) {
                int off = ft * 32 + quad * 8;
                f32x4 u0 = *(const f32x4*)(euN + r0 + off);
                f32x4 u1 = *(const f32x4*)(euN + r0 + off + 4);
                f32x4 v0 = *(const f32x4*)(euN + r0 + 128 + off);
                f32x4 v1 = *(const f32x4*)(euN + r0 + 128 + off + 4);
                bf16x8 a0, a1;
                #pragma unroll
                for (int e = 0; e < 4; ++e) {
                    a0[e] = (bf16)u0[e]; a0[4 + e] = (bf16)u1[e];
                    a1[e] = (bf16)v0[e]; a1[4 + e] = (bf16)v1[e];
                }
                c00 = MFMA(a0, w1r[0][ft], c00);
                c01 = MFMA(a0, w1r[1][ft], c01);
                c10 = MFMA(a1, w1r[0][ft], c10);
                c11 = MFMA(a1, w1r[1][ft], c11);
            }
            #pragma unroll
            for (int ft = 4; ft < 8; ++ft) {
                int off = (ft - 4) * 32 + quad * 8;
                f32x4 u0 = *(const f32x4*)(sfN + off);
                f32x4 u1 = *(const f32x4*)(sfN + off + 4);
                bf16x8 a;
                #pragma unroll
                for (int e = 0; e < 4; ++e) { a[e] = (bf16)u0[e]; a[4 + e] = (bf16)u1[e]; }
                c00 = MFMA(a, w1r[0][ft], c00);
                c01 = MFMA(a, w1r[1][ft], c01);
                c10 = MFMA(a, w1r[0][ft], c10);
                c11 = MFMA(a, w1r[1][ft], c11);
            }
            #pragma unroll
            for (int r = 0; r < 4; ++r) {
                int row = quad * 4 + r;
                h1N[row * H_STRIDE + nt0 * 16 + ln15]              = (bf16)fmaxf(c00[r] + bias1_0, 0.f);
                h1N[row * H_STRIDE + (nt0 + 1) * 16 + ln15]        = (bf16)fmaxf(c01[r] + bias1_1, 0.f);
                h1N[(16 + row) * H_STRIDE + nt0 * 16 + ln15]       = (bf16)fmaxf(c10[r] + bias1_0, 0.f);
                h1N[(16 + row) * H_STRIDE + (nt0 + 1) * 16 + ln15] = (bf16)fmaxf(c11[r] + bias1_1, 0.f);
            }
        }
        __syncthreads();
        #pragma unroll 1
        for (int nd = 0; nd < 2; ++nd) {
            const bf16* h1N = h1 + nd * KN * H_STRIDE;
            f32x4 d00 = {0.f,0.f,0.f,0.f}, d01 = d00, d10 = d00, d11 = d00;
            #pragma unroll
            for (int kt = 0; kt < 4; ++kt) {
                bf16x8 a0 = *(const bf16x8*)(h1N + ln15 * H_STRIDE + kt * 32 + quad * 8);
                bf16x8 a1 = *(const bf16x8*)(h1N + (16 + ln15) * H_STRIDE + kt * 32 + quad * 8);
                d00 = MFMA(a0, w2r[0][kt], d00);
                d01 = MFMA(a0, w2r[1][kt], d01);
                d10 = MFMA(a1, w2r[0][kt], d10);
                d11 = MFMA(a1, w2r[1][kt], d11);
            }
            #pragma unroll
            for (int r = 0; r < 4; ++r) {
                float p0 = w3_0 * fmaxf(d00[r] + bias2_0, 0.f)
                         + w3_1 * fmaxf(d01[r] + bias2_1, 0.f);
                float p1 = w3_0 * fmaxf(d10[r] + bias2_0, 0.f)
                         + w3_1 * fmaxf(d11[r] + bias2_1, 0.f);
                #pragma unroll
                for (int o = 1; o < 16; o <<= 1) {
                    p0 += __shfl_xor(p0, o);
                    p1 += __shfl_xor(p1, o);
                }
                if (ln15 == 0) {
                    lpart[nd][wave * KN + quad * 4 + r]      = p0;
                    lpart[nd][wave * KN + 16 + quad * 4 + r] = p1;
                }
            }
        }
        __syncthreads();
        if (wave < 2) {
            int nd = wave, k = lane & 31;
            float lg = lpart[nd][k] + lpart[nd][KN + k] + lpart[nd][2 * KN + k]
                     + lpart[nd][3 * KN + k] + b3v;
            int len = nd ? lenB : lenA;
            bool act = (lane < 32) && (k < len);
            float l = act ? lg : -1e30f;
            float m = l;
            #pragma unroll
            for (int o = 1; o < 32; o <<= 1) m = fmaxf(m, __shfl_xor(m, o));
            float e = act ? expf(l - m) : 0.f;
            float s = e;
            #pragma unroll
            for (int o = 1; o < 32; o <<= 1) s += __shfl_xor(s, o);
            if (lane < 32) att_s[nd][k] = (s > 0.f) ? (e / s) : 0.f;
        }
        __syncthreads();
        {
            int nd = t >> 7, d = t & 127;
            const float* euN = eu + nd * FB_EU_NODE_DW;
            float acc = 0.f;
            #pragma unroll
            for (int k = 0; k < KN; ++k)
                acc += att_s[nd][k] * euN[(k & 15) * FB_CHUNK_DW + ((k >> 4) << 7) + d];
            float sf = self_f[nd * D + d];
            int len = nd ? lenB : lenA;
            out[(size_t)(nA + nd) * D + d] = (len > 0) ? 0.5f * (acc + sf) : sf;
        }
        __syncthreads();
    }
}

extern "C" void kernel_launch(void* const* d_in, const int* in_sizes, int n_in,
                              void* d_out, int out_size, void* d_ws, size_t ws_size,
                              hipStream_t stream) {
    const int*   nodes     = (const int*)d_in[0];
    const int*   neigh_idx = (const int*)d_in[1];
    const int*   neigh_len = (const int*)d_in[2];
    const float* u2e       = (const float*)d_in[3];
    const float* W1        = (const float*)d_in[4];
    const float* b1        = (const float*)d_in[5];
    const float* W2        = (const float*)d_in[6];
    const float* b2        = (const float*)d_in[7];
    const float* W3        = (const float*)d_in[8];
    const float* b3        = (const float*)d_in[9];
    float* out = (float*)d_out;

    bf16*  w1p    = (bf16*)d_ws;                                  // 65536 B
    bf16*  w2p    = w1p + 32768;                                  // 32768 B
    bf16*  u2e_bf = (bf16*)((char*)d_ws + 98304);                 // 25.6 MB
    float* sv1t   = (float*)((char*)d_ws + 98304 + (size_t)VOCAB * D * 2); // 10.24 MB
    const size_t need = 98304ull + (size_t)VOCAB * D * 2 + (size_t)NNODES * D * 4;

    pack_weights_kernel<<<192, 256, 0, stream>>>(W1, W2, w1p, w2p);
    if (ws_size >= need) {
        convert_table_kernel<<<VOCAB * D / 2048, 256, 0, stream>>>(u2e, u2e_bf);
        sv1_kernel<<<SV1_BLOCKS, 256, 0, stream>>>(nodes, u2e_bf, w1p, sv1t);
        graphrec_agg_kernel<<<GRID, 256, 0, stream>>>(nodes, neigh_idx, neigh_len,
                                                      u2e, u2e_bf, sv1t, b1, b2,
                                                      W3, b3, w1p, w2p, out);
    } else {
        graphrec_agg_fb<<<GRID, 256, 0, stream>>>(nodes, neigh_idx, neigh_len, u2e,
                                                  b1, b2, W3, b3, w1p, w2p, out);
    }
}